// Round 4
// baseline (99.277 us; speedup 1.0000x reference)
//
#include <hip/hip_runtime.h>
#include <hip/hip_fp16.h>

// Problem constants (from reference)
#define BSZ     1024   // batch
#define N_IN    1024
#define NLAYERS 5
#define NPL     2048   // nodes per layer
#define FANIN   16
#define N_OUT   256
#define NCHUNK  8      // batch chunks == XCD count
#define CHB     (BSZ / NCHUNK)   // 128 batch elems per chunk
#define NPI     8      // nodes per work item (one block claim)

#define VALS_ROWS (N_IN + 4 * NPL)                              // 9216 rows
#define META_OFF  ((size_t)VALS_ROWS * BSZ * sizeof(__half))    // meta byte offset
#define SLOT_INTS 32                                            // 128B per counter slot
#define META_INTS (80 * SLOT_INTS)   // 40 ctr slots + 40 flag slots (5 layers x 8)

union H2 { unsigned int u; __half h[2]; };

__device__ __forceinline__ int xcc_id() {
    // HW_REG_XCC_ID = 20 (gfx940+); read full field, mask to 0..7.
    // If this encoding is ever wrong we get a garbage-but-valid chunk and the
    // steal loop still covers all work -> perf-neutral, never incorrect.
    return (int)(__builtin_amdgcn_s_getreg((31u << 11) | 20u) & 7u);
}

__device__ __forceinline__ float fast_tanh(float x) {
    // tanh(x) = 1 - 2/(exp(2x)+1); exact +-1 saturation at |x| large.
    float t = __expf(2.0f * x);
    return 1.0f - 2.0f / (t + 1.0f);
}
__device__ __forceinline__ float fast_sigmoid(float x) {
    return 1.0f / (1.0f + __expf(-x));
}

// ---------------------------------------------------------------------------
// Transpose inputs (B, N_IN) f32 -> vals_t (N_IN, B) fp16. Block 0 also zeros
// the work-queue meta region (visible to layer kernels at kernel boundary).
// ---------------------------------------------------------------------------
__global__ __launch_bounds__(1024) void transpose_in_kernel(
    const float* __restrict__ in, __half* __restrict__ out,
    int* __restrict__ meta)
{
    if (blockIdx.x == 0) {
        for (int i = threadIdx.x + threadIdx.y * 32; i < META_INTS; i += 1024)
            meta[i] = 0;
    }
    __shared__ float tile[32][33];
    const int c = blockIdx.x & 7;
    const int t = blockIdx.x >> 3;
    const int batch_tile = c * 4 + (t & 3);
    const int node_tile  = t >> 2;

    int x = node_tile * 32 + threadIdx.x;
    int y = batch_tile * 32 + threadIdx.y;
    tile[threadIdx.y][threadIdx.x] = in[(size_t)y * N_IN + x];
    __syncthreads();
    int oy = node_tile * 32 + threadIdx.y;
    int ox = batch_tile * 32 + threadIdx.x;
    out[(size_t)oy * BSZ + ox] = __float2half(tile[threadIdx.x][threadIdx.y]);
}

// ---------------------------------------------------------------------------
// Layer kernel with XCD-affine work queues. A block reads its physical XCD id
// and claims items (8 nodes x its XCD's 128-wide batch chunk) from that
// chunk's queue; steals from neighbors when empty. Gathers then hit the
// 4 MiB per-XCD L2 (footprint <= 2.3 MB/chunk) instead of L3.
// Block = 256 threads = 4 waves; wave handles 2 nodes x 128 batch (2/lane).
// ---------------------------------------------------------------------------
template<int ACT, int WRITE_OUT>
__global__ __launch_bounds__(256, 4) void layer_kernel(
    const __half* __restrict__ vals_t,  // [VALS_ROWS][BSZ] fp16
    void* __restrict__ dst,             // ==0: __half* row base; ==1: float* d_out
    const int* __restrict__ src,        // [NPL][FANIN]
    const float* __restrict__ w,        // [NPL][FANIN]
    const float* __restrict__ bias,     // [NPL]
    int node_base,                      // first node of this layer we compute
    int items_per_chunk,                // (#nodes)/NPI
    int* __restrict__ ctr,              // 8 slots, stride SLOT_INTS
    int* __restrict__ flg)              // 8 slots, stride SLOT_INTS
{
    __shared__ int s_item;
    const int wave = threadIdx.x >> 6;
    const int lane = threadIdx.x & 63;
    const int c0 = xcc_id();

    for (int d = 0; d < NCHUNK; ++d) {
        const int c = (c0 + d) & (NCHUNK - 1);
        int* pc = ctr + c * SLOT_INTS;
        int* pf = flg + c * SLOT_INTS;
        for (;;) {
            if (threadIdx.x == 0) {
                int t = -1;
                if (__hip_atomic_load(pf, __ATOMIC_RELAXED,
                                      __HIP_MEMORY_SCOPE_AGENT) == 0) {
                    t = atomicAdd(pc, 1);
                    if (t >= items_per_chunk) {
                        __hip_atomic_store(pf, 1, __ATOMIC_RELAXED,
                                           __HIP_MEMORY_SCOPE_AGENT);
                        t = -1;
                    }
                }
                s_item = t;
            }
            __syncthreads();
            const int item = s_item;
            __syncthreads();          // protect s_item from next claim
            if (item < 0) break;

            const int b = c * CHB + (lane << 1);
#pragma unroll
            for (int k = 0; k < 2; ++k) {
                const int n = __builtin_amdgcn_readfirstlane(
                    node_base + item * NPI + wave * 2 + k);
                const int*   s  = src + (size_t)n * FANIN;
                const float* ww = w   + (size_t)n * FANIN;
                const float  bv = bias[n];
                float a0 = bv, a1 = bv;
#pragma unroll
                for (int f = 0; f < FANIN; ++f) {
                    const int   idx = s[f];          // SGPR (scalar load)
                    const float wf  = ww[f];         // SGPR
                    H2 v;
                    v.u = *reinterpret_cast<const unsigned int*>(
                        vals_t + (size_t)idx * BSZ + b);
                    a0 = fmaf(__half2float(v.h[0]), wf, a0);
                    a1 = fmaf(__half2float(v.h[1]), wf, a1);
                }
                if (ACT == 0) { a0 = fast_tanh(a0);    a1 = fast_tanh(a1); }
                else          { a0 = fast_sigmoid(a0); a1 = fast_sigmoid(a1); }

                if (WRITE_OUT == 0) {
                    H2 o;
                    o.h[0] = __float2half(a0);
                    o.h[1] = __float2half(a1);
                    *reinterpret_cast<unsigned int*>(
                        (__half*)dst + (size_t)n * BSZ + b) = o.u;
                } else {
                    float* outp = (float*)dst;
                    const int j = n - node_base;
                    outp[(size_t)(b + 0) * N_OUT + j] = a0;
                    outp[(size_t)(b + 1) * N_OUT + j] = a1;
                }
            }
        }
    }
}

// ---------------------------------------------------------------------------
// Launch. vals_t = 18.9 MB fp16 in d_ws; work-queue meta right after it.
// Grid 2048 (8 blocks/CU target) == total items per full layer -> ~1 item per
// block, balanced per XCD when placement is even; stealing fixes the rest.
// ---------------------------------------------------------------------------
extern "C" void kernel_launch(void* const* d_in, const int* in_sizes, int n_in,
                              void* d_out, int out_size, void* d_ws, size_t ws_size,
                              hipStream_t stream)
{
    const float* inputs   = (const float*)d_in[0];
    const int*   edge_src = (const int*)  d_in[1];
    const float* edge_w   = (const float*)d_in[2];
    const float* biases   = (const float*)d_in[3];
    float*  out    = (float*)d_out;
    __half* vals_t = (__half*)d_ws;
    int*    meta   = (int*)((char*)d_ws + META_OFF);

    transpose_in_kernel<<<1024, dim3(32, 32), 0, stream>>>(inputs, vals_t, meta);

    for (int l = 0; l < NLAYERS - 1; ++l) {
        layer_kernel<0, 0><<<2048, 256, 0, stream>>>(
            vals_t,
            (void*)(vals_t + (size_t)(N_IN + (size_t)l * NPL) * BSZ),
            edge_src + (size_t)l * NPL * FANIN,
            edge_w   + (size_t)l * NPL * FANIN,
            biases   + (size_t)l * NPL,
            0, NPL / NPI,
            meta + (l * 8) * SLOT_INTS,
            meta + (40 + l * 8) * SLOT_INTS);
    }

    layer_kernel<1, 1><<<256, 256, 0, stream>>>(
        vals_t,
        (void*)out,
        edge_src + (size_t)4 * NPL * FANIN,
        edge_w   + (size_t)4 * NPL * FANIN,
        biases   + (size_t)4 * NPL,
        NPL - N_OUT, N_OUT / NPI,
        meta + (4 * 8) * SLOT_INTS,
        meta + (40 + 4 * 8) * SLOT_INTS);
}

// Round 5
// 30.143 us; speedup vs baseline: 3.2936x; 3.2936x over previous
//
#include <hip/hip_runtime.h>
#include <hip/hip_fp16.h>

// Problem constants (from reference)
#define BSZ     1024   // batch
#define N_IN    1024
#define NLAYERS 5
#define NPL     2048   // nodes per layer
#define FANIN   16
#define N_OUT   256

#define VALS_ROWS   (N_IN + 4 * NPL)            // 9216 gatherable rows
#define CPB         4                           // batch columns per block
#define NBLK        (BSZ / CPB)                 // 256 blocks
#define REGION_B    (VALS_ROWS * 2 * 2)         // 36864 B: rows x 2 cols x fp16
#define LDS_BYTES   (2 * REGION_B)              // 73728 B (cols 0-1, cols 2-3)

// ---------------------------------------------------------------------------
// Pack kernel: edge (idx, w) -> u32 = (lds_byte_off << 16) | fp16(w), stored
// transposed as packed[l][f][n] so the main kernel's per-lane loads (lane = n)
// are coalesced. lds_byte_off = idx*4 <= 36860 fits in 16 bits.
// ---------------------------------------------------------------------------
__global__ __launch_bounds__(256) void pack_edges_kernel(
    const int* __restrict__ src, const float* __restrict__ w,
    unsigned int* __restrict__ packed)
{
    int t = blockIdx.x * 256 + threadIdx.x;      // one (l, n) pair per thread
    if (t >= NLAYERS * NPL) return;
    int l = t / NPL, n = t - l * NPL;
    const int*   s  = src + ((size_t)l * NPL + n) * FANIN;
    const float* ww = w   + ((size_t)l * NPL + n) * FANIN;
#pragma unroll
    for (int f = 0; f < FANIN; ++f) {
        unsigned int off = (unsigned int)s[f] * 4u;             // LDS byte offset
        unsigned short hw = __half_as_ushort(__float2half(ww[f]));
        packed[((size_t)l * FANIN + f) * NPL + n] = (off << 16) | (unsigned int)hw;
    }
}

// ---------------------------------------------------------------------------
// Fused whole-network kernel. Each block owns 4 batch columns; ALL activations
// live in LDS (two regions: cols{0,1} and cols{2,3}, row stride 4B), so every
// gather is a ds_read_b32 at idx*4 (bank = idx%32, random ~2-way: near-free).
// 1024 threads = 16 waves; lane = node; per layer 2 node-sweeps; one
// __syncthreads per layer (layer l writes rows >= N_IN+l*NPL, reads below).
// Weights arrive as packed u32 (coalesced, L2-broadcast across blocks).
// ---------------------------------------------------------------------------
__device__ __forceinline__ float fast_tanh(float x) {
    float t = __expf(2.0f * x);
    return 1.0f - 2.0f / (t + 1.0f);
}
__device__ __forceinline__ float fast_sigmoid(float x) {
    return 1.0f / (1.0f + __expf(-x));
}

__global__ __launch_bounds__(1024) void fused_net_kernel(
    const float* __restrict__ inputs,           // (BSZ, N_IN) f32
    const unsigned int* __restrict__ packed,    // [L][FANIN][NPL]
    const float* __restrict__ biases,           // (L, NPL) f32
    float* __restrict__ out)                    // (BSZ, N_OUT) f32
{
    extern __shared__ char lds[];
    const int tid = threadIdx.x;
    const int c0  = blockIdx.x * CPB;           // batch base for this block

    // ---- load this block's 4 input columns into LDS rows [0, N_IN) ----
#pragma unroll
    for (int c = 0; c < CPB; ++c) {
        float v = inputs[(size_t)(c0 + c) * N_IN + tid];   // coalesced
        char* base = lds + (c < 2 ? 0 : REGION_B);
        *reinterpret_cast<__half*>(base + tid * 4 + (c & 1) * 2) = __float2half(v);
    }
    __syncthreads();

    // ---- layers 0..3: tanh, write LDS rows ----
    for (int l = 0; l < NLAYERS - 1; ++l) {
        const unsigned int* pkl = packed + (size_t)l * FANIN * NPL;
        const float* bl = biases + (size_t)l * NPL;
        const int wbase = N_IN + l * NPL;
#pragma unroll
        for (int it = 0; it < NPL / 1024; ++it) {
            const int n = it * 1024 + tid;      // lane-consecutive node
            unsigned int pk[FANIN];
#pragma unroll
            for (int f = 0; f < FANIN; ++f) pk[f] = pkl[f * NPL + n];  // coalesced
            const float bv = bl[n];
            float a0 = bv, a1 = bv, a2 = bv, a3 = bv;
#pragma unroll
            for (int f = 0; f < FANIN; ++f) {
                const unsigned int u  = pk[f];
                const unsigned int off = u >> 16;
                const __half hw = __ushort_as_half((unsigned short)(u & 0xffffu));
                const __half2 va = *reinterpret_cast<const __half2*>(lds + off);
                const __half2 vb = *reinterpret_cast<const __half2*>(lds + REGION_B + off);
                const float wf = __half2float(hw);          // fma_mix fodder
                a0 = fmaf(__half2float(va.x), wf, a0);
                a1 = fmaf(__half2float(va.y), wf, a1);
                a2 = fmaf(__half2float(vb.x), wf, a2);
                a3 = fmaf(__half2float(vb.y), wf, a3);
            }
            a0 = fast_tanh(a0); a1 = fast_tanh(a1);
            a2 = fast_tanh(a2); a3 = fast_tanh(a3);
            const int rd = (wbase + n) * 4;     // dest row byte offset
            *reinterpret_cast<__half2*>(lds + rd) =
                __halves2half2(__float2half(a0), __float2half(a1));
            *reinterpret_cast<__half2*>(lds + REGION_B + rd) =
                __halves2half2(__float2half(a2), __float2half(a3));
        }
        __syncthreads();
    }

    // ---- layer 4: only last N_OUT nodes reach the output; sigmoid; f32 out --
    if (tid < N_OUT) {
        const int n = (NPL - N_OUT) + tid;      // node within layer 4
        const unsigned int* pkl = packed + (size_t)(NLAYERS - 1) * FANIN * NPL;
        const float bv = biases[(size_t)(NLAYERS - 1) * NPL + n];
        unsigned int pk[FANIN];
#pragma unroll
        for (int f = 0; f < FANIN; ++f) pk[f] = pkl[f * NPL + n];
        float a0 = bv, a1 = bv, a2 = bv, a3 = bv;
#pragma unroll
        for (int f = 0; f < FANIN; ++f) {
            const unsigned int u  = pk[f];
            const unsigned int off = u >> 16;
            const __half hw = __ushort_as_half((unsigned short)(u & 0xffffu));
            const __half2 va = *reinterpret_cast<const __half2*>(lds + off);
            const __half2 vb = *reinterpret_cast<const __half2*>(lds + REGION_B + off);
            const float wf = __half2float(hw);
            a0 = fmaf(__half2float(va.x), wf, a0);
            a1 = fmaf(__half2float(va.y), wf, a1);
            a2 = fmaf(__half2float(vb.x), wf, a2);
            a3 = fmaf(__half2float(vb.y), wf, a3);
        }
        a0 = fast_sigmoid(a0); a1 = fast_sigmoid(a1);
        a2 = fast_sigmoid(a2); a3 = fast_sigmoid(a3);
        const int j = tid;                       // output column
        out[(size_t)(c0 + 0) * N_OUT + j] = a0;  // lane-consecutive j: coalesced
        out[(size_t)(c0 + 1) * N_OUT + j] = a1;
        out[(size_t)(c0 + 2) * N_OUT + j] = a2;
        out[(size_t)(c0 + 3) * N_OUT + j] = a3;
    }
}

// ---------------------------------------------------------------------------
// Launch: pack edges into d_ws (0.66 MB), then one fused kernel.
// 256 blocks x 1024 threads, 73728 B dynamic LDS per block (< 160 KiB/CU).
// ---------------------------------------------------------------------------
extern "C" void kernel_launch(void* const* d_in, const int* in_sizes, int n_in,
                              void* d_out, int out_size, void* d_ws, size_t ws_size,
                              hipStream_t stream)
{
    const float* inputs   = (const float*)d_in[0];
    const int*   edge_src = (const int*)  d_in[1];
    const float* edge_w   = (const float*)d_in[2];
    const float* biases   = (const float*)d_in[3];
    float* out = (float*)d_out;
    unsigned int* packed = (unsigned int*)d_ws;   // L*FANIN*NPL*4 B = 655,360 B

    pack_edges_kernel<<<(NLAYERS * NPL + 255) / 256, 256, 0, stream>>>(
        edge_src, edge_w, packed);

    fused_net_kernel<<<NBLK, 1024, LDS_BYTES, stream>>>(
        inputs, packed, biases, out);
}

// Round 6
// 27.284 us; speedup vs baseline: 3.6386x; 1.1048x over previous
//
#include <hip/hip_runtime.h>
#include <hip/hip_fp16.h>

// Problem constants (from reference)
#define BSZ     1024   // batch
#define N_IN    1024
#define NLAYERS 5
#define NPL     2048   // nodes per layer
#define FANIN   16
#define N_OUT   256

#define VALS_ROWS   (N_IN + 4 * NPL)            // 9216 gatherable rows
#define CPB         4                           // batch columns per block
#define NBLK        (BSZ / CPB)                 // 256 blocks
#define ROW_B       8                           // 4 cols x fp16 per row
#define LDS_BYTES   (VALS_ROWS * ROW_B)         // 73728 B

union H4 { unsigned long long u; __half2 h2[2]; };

// ---------------------------------------------------------------------------
// Pack kernel: edge (idx, w) -> u32 = (row_idx << 16) | fp16(w), stored
// transposed as packed[l][f][n] so the main kernel's per-lane loads (lane = n)
// are coalesced. row_idx <= 9215 fits in 14 bits.
// ---------------------------------------------------------------------------
__global__ __launch_bounds__(256) void pack_edges_kernel(
    const int* __restrict__ src, const float* __restrict__ w,
    unsigned int* __restrict__ packed)
{
    int t = blockIdx.x * 256 + threadIdx.x;      // one (l, n) pair per thread
    if (t >= NLAYERS * NPL) return;
    int l = t / NPL, n = t - l * NPL;
    const int*   s  = src + ((size_t)l * NPL + n) * FANIN;
    const float* ww = w   + ((size_t)l * NPL + n) * FANIN;
#pragma unroll
    for (int f = 0; f < FANIN; ++f) {
        unsigned int idx = (unsigned int)s[f];
        unsigned short hw = __half_as_ushort(__float2half(ww[f]));
        packed[((size_t)l * FANIN + f) * NPL + n] = (idx << 16) | (unsigned int)hw;
    }
}

// ---------------------------------------------------------------------------
// Fused whole-network kernel. Each block owns 4 batch columns; ALL activations
// live in LDS as 8-B row records [row][4 x fp16], so every gather is ONE
// ds_read_b64 serving 4 FMAs (b64/b128-class LDS throughput ~2x b32 per byte).
// 1024 threads = 16 waves; per layer 2 node-sweeps; one __syncthreads per
// layer (layer l writes rows >= N_IN+l*NPL, reads strictly below).
// Weights arrive as packed u32 (coalesced, L2-broadcast across blocks).
// ---------------------------------------------------------------------------
__device__ __forceinline__ float fast_tanh(float x) {
    float t = __expf(2.0f * x);
    return 1.0f - 2.0f / (t + 1.0f);
}
__device__ __forceinline__ float fast_sigmoid(float x) {
    return 1.0f / (1.0f + __expf(-x));
}

__global__ __launch_bounds__(1024) void fused_net_kernel(
    const float* __restrict__ inputs,           // (BSZ, N_IN) f32
    const unsigned int* __restrict__ packed,    // [L][FANIN][NPL]
    const float* __restrict__ biases,           // (L, NPL) f32
    float* __restrict__ out)                    // (BSZ, N_OUT) f32
{
    extern __shared__ char lds[];
    const int tid = threadIdx.x;
    const int c0  = blockIdx.x * CPB;           // batch base for this block

    // ---- load 4 input columns, pack row tid as 4xfp16, one ds_write_b64 ----
    {
        float v0 = inputs[(size_t)(c0 + 0) * N_IN + tid];   // each coalesced
        float v1 = inputs[(size_t)(c0 + 1) * N_IN + tid];
        float v2 = inputs[(size_t)(c0 + 2) * N_IN + tid];
        float v3 = inputs[(size_t)(c0 + 3) * N_IN + tid];
        H4 rec;
        rec.h2[0] = __halves2half2(__float2half(v0), __float2half(v1));
        rec.h2[1] = __halves2half2(__float2half(v2), __float2half(v3));
        *reinterpret_cast<unsigned long long*>(lds + (size_t)tid * ROW_B) = rec.u;
    }
    __syncthreads();

    // ---- layers 0..3: tanh, write LDS rows ----
    for (int l = 0; l < NLAYERS - 1; ++l) {
        const unsigned int* pkl = packed + (size_t)l * FANIN * NPL;
        const float* bl = biases + (size_t)l * NPL;
        const int wbase = N_IN + l * NPL;
#pragma unroll
        for (int it = 0; it < NPL / 1024; ++it) {
            const int n = it * 1024 + tid;      // lane-consecutive node
            unsigned int pk[FANIN];
#pragma unroll
            for (int f = 0; f < FANIN; ++f) pk[f] = pkl[f * NPL + n];  // coalesced
            const float bv = bl[n];
            float a0 = bv, a1 = bv, a2 = bv, a3 = bv;
#pragma unroll
            for (int f = 0; f < FANIN; ++f) {
                const unsigned int u   = pk[f];
                const unsigned int off = (u >> 16) << 3;    // row byte offset
                H4 v;
                v.u = *reinterpret_cast<const unsigned long long*>(lds + off);
                const float wf = __half2float(
                    __ushort_as_half((unsigned short)(u & 0xffffu)));
                a0 = fmaf(__half2float(v.h2[0].x), wf, a0);
                a1 = fmaf(__half2float(v.h2[0].y), wf, a1);
                a2 = fmaf(__half2float(v.h2[1].x), wf, a2);
                a3 = fmaf(__half2float(v.h2[1].y), wf, a3);
            }
            a0 = fast_tanh(a0); a1 = fast_tanh(a1);
            a2 = fast_tanh(a2); a3 = fast_tanh(a3);
            H4 rec;
            rec.h2[0] = __halves2half2(__float2half(a0), __float2half(a1));
            rec.h2[1] = __halves2half2(__float2half(a2), __float2half(a3));
            *reinterpret_cast<unsigned long long*>(
                lds + (size_t)(wbase + n) * ROW_B) = rec.u;
        }
        __syncthreads();
    }

    // ---- layer 4: only last N_OUT nodes reach the output; sigmoid; f32 out --
    if (tid < N_OUT) {
        const int n = (NPL - N_OUT) + tid;      // node within layer 4
        const unsigned int* pkl = packed + (size_t)(NLAYERS - 1) * FANIN * NPL;
        const float bv = biases[(size_t)(NLAYERS - 1) * NPL + n];
        unsigned int pk[FANIN];
#pragma unroll
        for (int f = 0; f < FANIN; ++f) pk[f] = pkl[f * NPL + n];
        float a0 = bv, a1 = bv, a2 = bv, a3 = bv;
#pragma unroll
        for (int f = 0; f < FANIN; ++f) {
            const unsigned int u   = pk[f];
            const unsigned int off = (u >> 16) << 3;
            H4 v;
            v.u = *reinterpret_cast<const unsigned long long*>(lds + off);
            const float wf = __half2float(
                __ushort_as_half((unsigned short)(u & 0xffffu)));
            a0 = fmaf(__half2float(v.h2[0].x), wf, a0);
            a1 = fmaf(__half2float(v.h2[0].y), wf, a1);
            a2 = fmaf(__half2float(v.h2[1].x), wf, a2);
            a3 = fmaf(__half2float(v.h2[1].y), wf, a3);
        }
        a0 = fast_sigmoid(a0); a1 = fast_sigmoid(a1);
        a2 = fast_sigmoid(a2); a3 = fast_sigmoid(a3);
        const int j = tid;                       // output column
        out[(size_t)(c0 + 0) * N_OUT + j] = a0;  // lane-consecutive j: coalesced
        out[(size_t)(c0 + 1) * N_OUT + j] = a1;
        out[(size_t)(c0 + 2) * N_OUT + j] = a2;
        out[(size_t)(c0 + 3) * N_OUT + j] = a3;
    }
}

// ---------------------------------------------------------------------------
// Launch: pack edges into d_ws (0.66 MB), then one fused kernel.
// 256 blocks x 1024 threads, 73728 B dynamic LDS per block.
// ---------------------------------------------------------------------------
extern "C" void kernel_launch(void* const* d_in, const int* in_sizes, int n_in,
                              void* d_out, int out_size, void* d_ws, size_t ws_size,
                              hipStream_t stream)
{
    const float* inputs   = (const float*)d_in[0];
    const int*   edge_src = (const int*)  d_in[1];
    const float* edge_w   = (const float*)d_in[2];
    const float* biases   = (const float*)d_in[3];
    float* out = (float*)d_out;
    unsigned int* packed = (unsigned int*)d_ws;   // L*FANIN*NPL*4 B = 655,360 B

    pack_edges_kernel<<<(NLAYERS * NPL + 255) / 256, 256, 0, stream>>>(
        edge_src, edge_w, packed);

    fused_net_kernel<<<NBLK, 1024, LDS_BYTES, stream>>>(
        inputs, packed, biases, out);
}

// Round 7
// 25.970 us; speedup vs baseline: 3.8227x; 1.0506x over previous
//
#include <hip/hip_runtime.h>
#include <hip/hip_fp16.h>

// Problem constants (from reference)
#define BSZ     1024   // batch
#define N_IN    1024
#define NLAYERS 5
#define NPL     2048   // nodes per layer
#define FANIN   16
#define N_OUT   256

#define VALS_ROWS   (N_IN + 4 * NPL)            // 9216 gatherable rows
#define CPB         4                           // batch columns per block
#define NBLK        (BSZ / CPB)                 // 256 blocks
#define ROW_B       8                           // 4 cols x fp16 per row
#define LDS_BYTES   (VALS_ROWS * ROW_B)         // 73728 B

union H4 { unsigned long long u; __half2 h2[2]; };

// ---------------------------------------------------------------------------
// Pack kernel. Layout [l*NPL+n][FANIN] (lane-local 64B -> dwordx4 loads).
// Per node: sort its 16 edges by LDS bank-pair (idx & 15) using a static-index
// rank computation (no dynamic reg indexing -> no scratch), then store rotated
// by n: slot f holds the rank-((f+n)&15) edge. At gather step f, the 64 lanes
// of a wave (consecutive n) present each rank exactly 4x -> near-uniform bank
// spread instead of Poisson collisions. Sum order change is harmless (f32).
// Value = (off_hi << 16) | fp16(w); off_hi = idx*8 (byte offset, fits 16 bits
// for tanh layers since idx < 7168) or raw idx for the final layer.
// ---------------------------------------------------------------------------
__global__ __launch_bounds__(256) void pack_edges_kernel(
    const int* __restrict__ src, const float* __restrict__ wsrc,
    unsigned int* __restrict__ packed)
{
    int t = blockIdx.x * 256 + threadIdx.x;      // one (l, n) pair per thread
    if (t >= NLAYERS * NPL) return;
    const int l = t / NPL;
    const int n = t - l * NPL;
    const int*   s  = src  + (size_t)t * FANIN;
    const float* ww = wsrc + (size_t)t * FANIN;

    int          key[FANIN];
    unsigned int val[FANIN];
#pragma unroll
    for (int f = 0; f < FANIN; ++f) {
        unsigned int idx = (unsigned int)s[f];
        key[f] = (int)(idx & 15u);                       // bank-pair of ds_read_b64
        unsigned int hi = (l < NLAYERS - 1) ? (idx << 3) // pre-shifted byte offset
                                            : idx;       // final layer: raw idx
        unsigned short hw = __half_as_ushort(__float2half(ww[f]));
        val[f] = (hi << 16) | (unsigned int)hw;
    }

    unsigned int* dst = packed + (size_t)t * FANIN;
#pragma unroll
    for (int f = 0; f < FANIN; ++f) {
        int rank = 0;
#pragma unroll
        for (int g = 0; g < FANIN; ++g)
            rank += (key[g] < key[f]) || (key[g] == key[f] && g < f);
        dst[(rank - n) & 15] = val[f];                   // rotated sorted order
    }
}

// ---------------------------------------------------------------------------
// Fused whole-network kernel. Each block owns 4 batch columns; all activations
// in LDS as 8-B rows [row][4 x fp16]; gathers are single ds_read_b64 with a
// bank-balanced schedule. pk loads are 4x dwordx4 per sweep, double-buffered
// (pkA/pkB) and issued before the dependent compute / before the layer
// barrier so L2 latency hides under FMA+LDS work.
// ---------------------------------------------------------------------------
__device__ __forceinline__ float fast_tanh(float x) {
    float t = __expf(2.0f * x);
    return 1.0f - 2.0f / (t + 1.0f);
}
__device__ __forceinline__ float fast_sigmoid(float x) {
    return 1.0f / (1.0f + __expf(-x));
}

__global__ __launch_bounds__(1024) void fused_net_kernel(
    const float* __restrict__ inputs,           // (BSZ, N_IN) f32
    const unsigned int* __restrict__ packed,    // [l*NPL+n][FANIN]
    const float* __restrict__ biases,           // (L, NPL) f32
    float* __restrict__ out)                    // (BSZ, N_OUT) f32
{
    extern __shared__ char lds[];
    const int tid = threadIdx.x;
    const int c0  = blockIdx.x * CPB;           // batch base for this block

    // ---- stage 4 input columns as one 8-B row record per node ----
    {
        float v0 = inputs[(size_t)(c0 + 0) * N_IN + tid];
        float v1 = inputs[(size_t)(c0 + 1) * N_IN + tid];
        float v2 = inputs[(size_t)(c0 + 2) * N_IN + tid];
        float v3 = inputs[(size_t)(c0 + 3) * N_IN + tid];
        H4 rec;
        rec.h2[0] = __halves2half2(__float2half(v0), __float2half(v1));
        rec.h2[1] = __halves2half2(__float2half(v2), __float2half(v3));
        *reinterpret_cast<unsigned long long*>(lds + (size_t)tid * ROW_B) = rec.u;
    }
    __syncthreads();

    unsigned int pkA[FANIN], pkB[FANIN];

    // preload layer 0, sweep 0
#pragma unroll
    for (int f = 0; f < FANIN; ++f)
        pkA[f] = packed[(size_t)tid * FANIN + f];

    for (int l = 0; l < NLAYERS - 1; ++l) {
        const float* bl = biases + (size_t)l * NPL;
        const int wbase = N_IN + l * NPL;

        // issue sweep-1 pk loads before sweep-0 compute
#pragma unroll
        for (int f = 0; f < FANIN; ++f)
            pkB[f] = packed[((size_t)l * NPL + 1024 + tid) * FANIN + f];

        // ---- sweep 0 (nodes tid) using pkA ----
        {
            const int n = tid;
            const float bv = bl[n];
            float a0 = bv, a1 = bv, a2 = bv, a3 = bv;
#pragma unroll
            for (int f = 0; f < FANIN; ++f) {
                const unsigned int u   = pkA[f];
                const unsigned int off = u >> 16;        // pre-shifted byte off
                H4 v;
                v.u = *reinterpret_cast<const unsigned long long*>(lds + off);
                const float wf = __half2float(
                    __ushort_as_half((unsigned short)(u & 0xffffu)));
                a0 = fmaf(__half2float(v.h2[0].x), wf, a0);
                a1 = fmaf(__half2float(v.h2[0].y), wf, a1);
                a2 = fmaf(__half2float(v.h2[1].x), wf, a2);
                a3 = fmaf(__half2float(v.h2[1].y), wf, a3);
            }
            a0 = fast_tanh(a0); a1 = fast_tanh(a1);
            a2 = fast_tanh(a2); a3 = fast_tanh(a3);
            H4 rec;
            rec.h2[0] = __halves2half2(__float2half(a0), __float2half(a1));
            rec.h2[1] = __halves2half2(__float2half(a2), __float2half(a3));
            *reinterpret_cast<unsigned long long*>(
                lds + (size_t)(wbase + n) * ROW_B) = rec.u;
        }

        // issue NEXT-layer sweep-0 pk loads (or final-layer pk) before the
        // barrier: latency hides under sweep-1 compute + barrier drain
        if (l < NLAYERS - 2) {
#pragma unroll
            for (int f = 0; f < FANIN; ++f)
                pkA[f] = packed[((size_t)(l + 1) * NPL + tid) * FANIN + f];
        } else if (tid < N_OUT) {
            const int n4 = NPL - N_OUT + tid;
#pragma unroll
            for (int f = 0; f < FANIN; ++f)
                pkA[f] = packed[((size_t)(NLAYERS - 1) * NPL + n4) * FANIN + f];
        }

        // ---- sweep 1 (nodes 1024+tid) using pkB ----
        {
            const int n = 1024 + tid;
            const float bv = bl[n];
            float a0 = bv, a1 = bv, a2 = bv, a3 = bv;
#pragma unroll
            for (int f = 0; f < FANIN; ++f) {
                const unsigned int u   = pkB[f];
                const unsigned int off = u >> 16;
                H4 v;
                v.u = *reinterpret_cast<const unsigned long long*>(lds + off);
                const float wf = __half2float(
                    __ushort_as_half((unsigned short)(u & 0xffffu)));
                a0 = fmaf(__half2float(v.h2[0].x), wf, a0);
                a1 = fmaf(__half2float(v.h2[0].y), wf, a1);
                a2 = fmaf(__half2float(v.h2[1].x), wf, a2);
                a3 = fmaf(__half2float(v.h2[1].y), wf, a3);
            }
            a0 = fast_tanh(a0); a1 = fast_tanh(a1);
            a2 = fast_tanh(a2); a3 = fast_tanh(a3);
            H4 rec;
            rec.h2[0] = __halves2half2(__float2half(a0), __float2half(a1));
            rec.h2[1] = __halves2half2(__float2half(a2), __float2half(a3));
            *reinterpret_cast<unsigned long long*>(
                lds + (size_t)(wbase + n) * ROW_B) = rec.u;
        }
        __syncthreads();
    }

    // ---- layer 4: last N_OUT nodes only; sigmoid; f32 out (pk in pkA) ----
    if (tid < N_OUT) {
        const int n = NPL - N_OUT + tid;
        const float bv = biases[(size_t)(NLAYERS - 1) * NPL + n];
        float a0 = bv, a1 = bv, a2 = bv, a3 = bv;
#pragma unroll
        for (int f = 0; f < FANIN; ++f) {
            const unsigned int u   = pkA[f];
            const unsigned int off = (u >> 16) << 3;     // raw idx -> byte off
            H4 v;
            v.u = *reinterpret_cast<const unsigned long long*>(lds + off);
            const float wf = __half2float(
                __ushort_as_half((unsigned short)(u & 0xffffu)));
            a0 = fmaf(__half2float(v.h2[0].x), wf, a0);
            a1 = fmaf(__half2float(v.h2[0].y), wf, a1);
            a2 = fmaf(__half2float(v.h2[1].x), wf, a2);
            a3 = fmaf(__half2float(v.h2[1].y), wf, a3);
        }
        a0 = fast_sigmoid(a0); a1 = fast_sigmoid(a1);
        a2 = fast_sigmoid(a2); a3 = fast_sigmoid(a3);
        const int j = tid;                               // output column
        out[(size_t)(c0 + 0) * N_OUT + j] = a0;
        out[(size_t)(c0 + 1) * N_OUT + j] = a1;
        out[(size_t)(c0 + 2) * N_OUT + j] = a2;
        out[(size_t)(c0 + 3) * N_OUT + j] = a3;
    }
}

// ---------------------------------------------------------------------------
// Launch: pack (sort+rotate) edges into d_ws (0.66 MB), then one fused kernel.
// 256 blocks x 1024 threads, 73728 B dynamic LDS per block.
// ---------------------------------------------------------------------------
extern "C" void kernel_launch(void* const* d_in, const int* in_sizes, int n_in,
                              void* d_out, int out_size, void* d_ws, size_t ws_size,
                              hipStream_t stream)
{
    const float* inputs   = (const float*)d_in[0];
    const int*   edge_src = (const int*)  d_in[1];
    const float* edge_w   = (const float*)d_in[2];
    const float* biases   = (const float*)d_in[3];
    float* out = (float*)d_out;
    unsigned int* packed = (unsigned int*)d_ws;   // L*NPL*FANIN*4 B = 655,360 B

    pack_edges_kernel<<<(NLAYERS * NPL + 255) / 256, 256, 0, stream>>>(
        edge_src, edge_w, packed);

    fused_net_kernel<<<NBLK, 1024, LDS_BYTES, stream>>>(
        inputs, packed, biases, out);
}